// Round 6
// baseline (61.694 us; speedup 1.0000x reference)
//
#include <hip/hip_runtime.h>
#include <math.h>

// Problem constants
#define NB     16384
#define NJOINT 14
#define NCOL   14
#define NPIX   196            // 14*14 == 49 float4 exactly
#define NTASKS (NB * NJOINT)  // 229376
#define RAD    4

#define BLOCK1 256
#define GRID1  (NTASKS / BLOCK1)   // 896 blocks

typedef float f4 __attribute__((ext_vector_type(4)));

// Workspace layout: [0] acc_s (double), [8] acc_n (double), [16] counter (u32)
// All zeroed by a 32-byte memset node each call.

__global__ __launch_bounds__(BLOCK1) void mse2_fused(
    const float* __restrict__ osp,   // [B, 2*NJ, 196]
    const float* __restrict__ h,     // [B, NJ, 196]
    const float* __restrict__ t,     // [B, NJ, 2]
    const float* __restrict__ v,     // [B, NJ, 2]
    double* __restrict__ acc_s,
    double* __restrict__ acc_n,
    unsigned int* __restrict__ counter,
    float* __restrict__ out)
{
    __shared__ float tbl[NPIX];      // tbl[p*14+o]: 1-D gaussian response, delta at p, output o
    __shared__ float rmax[NCOL];     // row max (row min is exactly 0: 9-tap support < 14)
    __shared__ double sd[BLOCK1], sn[BLOCK1];

    const int tid = threadIdx.x;

    // ---- one task per thread: load small per-task inputs first (hide latency under table build)
    const int task = blockIdx.x * BLOCK1 + tid;   // always < NTASKS (exact fit)
    const float2 tv = reinterpret_cast<const float2*>(t)[task];
    const float t0 = tv.x;
    const float t1 = tv.y;
    const float v0 = reinterpret_cast<const float2*>(v)[task].x;

    // ---- build the 14x14 separable-gaussian table once per block ----
    if (tid < NPIX) {
        double kd[2 * RAD + 1];
        double ks = 0.0;
        #pragma unroll
        for (int d = 0; d <= 2 * RAD; ++d) {
            double xx = (double)(d - RAD);
            kd[d] = exp(-0.5 * xx * xx);
            ks += kd[d];
        }
        const int p = tid / NCOL, o = tid % NCOL;
        float s = 0.f;
        #pragma unroll
        for (int d = 0; d <= 2 * RAD; ++d) {
            int i = o + d;                                     // padded index 0..21
            int m = (i < RAD) ? (RAD - 1 - i)                  // symmetric reflect left
                  : (i < RAD + NCOL) ? (i - RAD)
                  : (2 * (RAD + NCOL) - 1 - i - RAD);          // 31 - i
            if (m == p) s += (float)(kd[d] / ks);
        }
        tbl[p * NCOL + o] = s;
    }
    __syncthreads();
    if (tid < NCOL) {
        float mxv = tbl[tid * NCOL];
        for (int o = 1; o < NCOL; ++o) mxv = fmaxf(mxv, tbl[tid * NCOL + o]);
        rmax[tid] = mxv;
    }
    __syncthreads();

    const bool vis = ((int)v0) == 1;
    const float visf = vis ? 1.f : 0.f;

    // splat center (trunc + clip, matches reference)
    const int xi = min(NCOL - 1, max(0, (int)(t0 * (float)NCOL)));
    const int yi = min(NCOL - 1, max(0, (int)(t1 * (float)NCOL)));
    const float inv = 1.f / (rmax[yi] * rmax[xi]);   // min of outer product == 0 exactly

    // gaussian rows in registers; fold inv + visibility into the x-row
    float gys[NCOL], gxs[NCOL];
    #pragma unroll
    for (int k = 0; k < NCOL; ++k) {
        gys[k] = tbl[yi * NCOL + k];
        gxs[k] = vis ? tbl[xi * NCOL + k] * inv : 0.f;
    }

    const f4* __restrict__ hb4 =
        reinterpret_cast<const f4*>(h + (size_t)task * NPIX);

    float acc  = 0.f;    // d1 partial
    float mval = -1.f;
    int   midx = 0;

    #pragma unroll
    for (int q = 0; q < NPIX / 4; ++q) {
        const f4 hv4 = hb4[q];
        #pragma unroll
        for (int j = 0; j < 4; ++j) {
            const int el = 4 * q + j;            // compile-time constant
            const int y = el / NCOL;             // compile-time
            const int x = el - y * NCOL;         // compile-time
            const float hv = hv4[j];
            // first-occurrence argmax (ascending el)
            if (hv > mval) { mval = hv; midx = el; }
            const float tgt = gys[y] * gxs[x];   // == gn (visible) or 0 (invisible)
            const float d   = hv - tgt;
            const float c   = d * d;
            // invisible: row 0 of diff zeroed (visf=0); visible: full
            acc += (y == 0) ? visf * c : c;
        }
    }

    // d2 + N contribution (per-thread)
    float d2v = 0.f, nv = 0.f;
    if (vis) {
        nv = v0;   // == 1
        const int yC = midx / NCOL;
        const int xC = midx - yC * NCOL;
        const int b  = task / NJOINT;
        const int j  = task - b * NJOINT;
        const float* __restrict__ ob = osp + ((size_t)b * (2 * NJOINT) + j) * NPIX;
        const float osx = ob[midx];
        const float osy = ob[(size_t)NJOINT * NPIX + midx];
        const bool cond = mval > 0.5f;
        const float sc = 1.0f / (float)NCOL;
        const float x0 = cond ? (osx + (float)xC) * sc : 0.f;
        const float x1 = cond ? (osy + (float)yC) * sc : 0.f;
        const float dx = x0 - t0;
        const float dy = x1 - t1;
        d2v = dx * dx + dy * dy;
    }

    // ---- deterministic block reduction (doubles, LDS tree) ----
    sd[tid] = (double)acc + (double)d2v;
    sn[tid] = (double)nv;
    __syncthreads();
    #pragma unroll
    for (int off = BLOCK1 / 2; off > 0; off >>= 1) {
        if (tid < off) {
            sd[tid] += sd[tid + off];
            sn[tid] += sn[tid + off];
        }
        __syncthreads();
    }

    // ---- fuse the final reduction with pure device-scope atomics (NO fences,
    //      no buffer_wbl2/buffer_inv: that was R4's 5x regression) ----
    if (tid == 0) {
        atomicAdd(acc_s, sd[0]);               // coherent RMW at coherence point
        atomicAdd(acc_n, sn[0]);
        // ensure both adds have completed before announcing via the counter
        asm volatile("s_waitcnt vmcnt(0)" ::: "memory");
        const unsigned int old =
            __hip_atomic_fetch_add(counter, 1u, __ATOMIC_RELAXED,
                                   __HIP_MEMORY_SCOPE_AGENT);
        if (old == GRID1 - 1) {
            // last finishing block: coherent read-back via RMW(+0.0)
            const double s = atomicAdd(acc_s, 0.0);
            const double n = atomicAdd(acc_n, 0.0);
            out[0] = (float)(s / n);
        }
    }
}

extern "C" void kernel_launch(void* const* d_in, const int* in_sizes, int n_in,
                              void* d_out, int out_size, void* d_ws, size_t ws_size,
                              hipStream_t stream) {
    const float* osp = (const float*)d_in[0];
    const float* h   = (const float*)d_in[1];
    // d_in[2] = op, unused by the reference
    const float* t   = (const float*)d_in[3];
    const float* v   = (const float*)d_in[4];

    double* acc_s = (double*)d_ws;
    double* acc_n = (double*)((char*)d_ws + 8);
    unsigned int* counter = (unsigned int*)((char*)d_ws + 16);
    float* out = (float*)d_out;

    // zero accumulators + counter (graph-capturable memset node)
    hipMemsetAsync(d_ws, 0, 32, stream);
    mse2_fused<<<GRID1, BLOCK1, 0, stream>>>(osp, h, t, v, acc_s, acc_n, counter, out);
}